// Round 1
// baseline (202.778 us; speedup 1.0000x reference)
//
#include <hip/hip_runtime.h>

#define T_TEST 8192
#define BB 8
#define FF 100
#define HH 512
#define KP 128   // padded K for layer 1

typedef __bf16 bf16x8 __attribute__((ext_vector_type(8)));
typedef float f32x4 __attribute__((ext_vector_type(4)));

__device__ __forceinline__ unsigned short f2bf(float f) {
    unsigned int u = __float_as_uint(f);
    u += 0x7fffu + ((u >> 16) & 1);   // RNE
    return (unsigned short)(u >> 16);
}

__device__ __forceinline__ float nan2num(float v) {
    unsigned int u = __float_as_uint(v);
    if ((u & 0x7f800000u) == 0x7f800000u) {
        v = (u & 0x007fffffu) ? 0.f : ((u >> 31) ? -3.3895314e38f : 3.3895314e38f);
    }
    return v;
}

__device__ __forceinline__ void gl_lds16(const unsigned short* g, unsigned short* l) {
    __builtin_amdgcn_global_load_lds(
        (const __attribute__((address_space(1))) unsigned int*)g,
        (__attribute__((address_space(3))) unsigned int*)l, 16, 0, 0);
}

// ---- prep kernels ------------------------------------------------------

// xb[b][t][k] = (k<100) ? bf16(nan2num(x[t][b][k])) : 0        (8*8192*128)
__global__ void prep_x(const float* __restrict__ x, unsigned short* __restrict__ xb) {
    int i = blockIdx.x * 256 + threadIdx.x;
    int b = i >> 20;            // 8192*128 = 1048576 per b
    int r = i & 1048575;
    int t = r >> 7;
    int k = r & 127;
    float v = 0.f;
    if (k < FF) v = nan2num(x[(t * BB + b) * FF + k]);
    xb[i] = f2bf(v);
}

// w1b[b][n][k] = (k<100) ? bf16(w1[b][k][n]) : 0               (8*512*128)
__global__ void prep_w1(const float* __restrict__ w1, unsigned short* __restrict__ w1b) {
    int i = blockIdx.x * 256 + threadIdx.x;
    int b = i >> 16;            // 512*128 per b
    int r = i & 65535;
    int k = r >> 9;             // consecutive threads vary n -> coalesced reads
    int n = r & 511;
    float v = 0.f;
    if (k < FF) v = w1[b * FF * HH + k * HH + n];
    w1b[(b << 16) + n * KP + k] = f2bf(v);
}

// w2b[b][n][k] = bf16(w2[b][k][n])                              (8*512*512)
__global__ void prep_w2(const float* __restrict__ w2, unsigned short* __restrict__ w2b) {
    int i = blockIdx.x * 256 + threadIdx.x;
    int b = i >> 18;            // 512*512 per b
    int r = i & 262143;
    int k = r >> 9;             // consecutive threads vary n -> coalesced reads
    int n = r & 511;
    float v = w2[b * HH * HH + k * HH + n];
    w2b[(b << 18) + n * HH + k] = f2bf(v);
}

// out[t*8+b] = b3[b]
__global__ void init_out(const float* __restrict__ b3, float* __restrict__ out) {
    int i = blockIdx.x * 256 + threadIdx.x;
    out[i] = b3[i & 7];
}

// ---- GEMM --------------------------------------------------------------
// MODE 1: h1 = relu(A*B^T + b1) stored bf16. MODE 2: out += dot(relu(A*B^T + b2), w3)
template <int MODE, int KSTEPS, int LDA>
__global__ void gemm_kernel(const unsigned short* __restrict__ Aall,
                            const unsigned short* __restrict__ Ball,
                            const float* __restrict__ bias,
                            const float* __restrict__ w3,
                            unsigned short* __restrict__ h1out,
                            float* __restrict__ out) {
    __shared__ __align__(16) unsigned short lds_a[128 * 32];
    __shared__ __align__(16) unsigned short lds_b[128 * 32];
    const int tid = threadIdx.x;
    const int mt = blockIdx.x, nt = blockIdx.y, b = blockIdx.z;
    const int m0 = mt * 128, n0 = nt * 128;
    const unsigned short* A = Aall + (size_t)b * T_TEST * LDA + (size_t)m0 * LDA;
    const unsigned short* Bm = Ball + (size_t)b * HH * LDA + (size_t)n0 * LDA;

    const int srow = tid >> 2;
    const int scol = (tid & 3) * 8;

    const int lane = tid & 63;
    const int wid = tid >> 6;
    const int wm = wid >> 1, wn = wid & 1;
    const int c = lane & 15, q = lane >> 4;

    f32x4 acc[4][4] = {};

    for (int ks = 0; ks < KSTEPS; ++ks) {
        const int k0 = ks * 32;
        gl_lds16(A + srow * LDA + k0 + scol, lds_a + tid * 8);
        gl_lds16(A + (srow + 64) * LDA + k0 + scol, lds_a + 2048 + tid * 8);
        gl_lds16(Bm + srow * LDA + k0 + scol, lds_b + tid * 8);
        gl_lds16(Bm + (srow + 64) * LDA + k0 + scol, lds_b + 2048 + tid * 8);
        __syncthreads();
        bf16x8 af[4], bfr[4];
#pragma unroll
        for (int i = 0; i < 4; ++i) {
            af[i]  = *reinterpret_cast<const bf16x8*>(lds_a + (wm * 64 + i * 16 + c) * 32 + q * 8);
            bfr[i] = *reinterpret_cast<const bf16x8*>(lds_b + (wn * 64 + i * 16 + c) * 32 + q * 8);
        }
#pragma unroll
        for (int mi = 0; mi < 4; ++mi)
#pragma unroll
            for (int ni = 0; ni < 4; ++ni)
                acc[mi][ni] = __builtin_amdgcn_mfma_f32_16x16x32_bf16(af[mi], bfr[ni], acc[mi][ni], 0, 0, 0);
        __syncthreads();
    }

    const int mb = m0 + wm * 64;
    const int nb = n0 + wn * 64;

    if (MODE == 1) {
        unsigned int* h32 = (unsigned int*)h1out;
#pragma unroll
        for (int mi = 0; mi < 4; ++mi) {
#pragma unroll
            for (int ni = 0; ni < 4; ++ni) {
                int n = nb + ni * 16 + c;
                float bv = bias[b * HH + n];
                unsigned short r0 = f2bf(fmaxf(acc[mi][ni][0] + bv, 0.f));
                unsigned short r1 = f2bf(fmaxf(acc[mi][ni][1] + bv, 0.f));
                unsigned short r2 = f2bf(fmaxf(acc[mi][ni][2] + bv, 0.f));
                unsigned short r3 = f2bf(fmaxf(acc[mi][ni][3] + bv, 0.f));
                unsigned int own01 = (unsigned int)r0 | ((unsigned int)r1 << 16);
                unsigned int own23 = (unsigned int)r2 | ((unsigned int)r3 << 16);
                unsigned int oth01 = __shfl_xor(own01, 1, 64);
                unsigned int oth23 = __shfl_xor(own23, 1, 64);
                int row0 = mb + mi * 16 + q * 4;
                int ncol = n & ~1;
                size_t e0 = ((size_t)(b * T_TEST + row0)) * HH + ncol;
                if (!(c & 1)) {
                    // rows row0, row0+1 ; this lane = even column (lo half)
                    unsigned int d0 = (own01 & 0xffffu) | (oth01 << 16);
                    unsigned int d1 = (own01 >> 16) | (oth01 & 0xffff0000u);
                    h32[e0 >> 1] = d0;
                    h32[(e0 + HH) >> 1] = d1;
                } else {
                    // rows row0+2, row0+3 ; this lane = odd column (hi half)
                    unsigned int d2 = (oth23 & 0xffffu) | (own23 << 16);
                    unsigned int d3 = (oth23 >> 16) | (own23 & 0xffff0000u);
                    h32[(e0 + 2 * HH) >> 1] = d2;
                    h32[(e0 + 3 * HH) >> 1] = d3;
                }
            }
        }
    } else {
        float psum[4][4] = {};  // [mi][reg]
#pragma unroll
        for (int ni = 0; ni < 4; ++ni) {
            int n = nb + ni * 16 + c;
            float bv = bias[b * HH + n];
            float wv = w3[b * HH + n];
#pragma unroll
            for (int mi = 0; mi < 4; ++mi)
#pragma unroll
                for (int r = 0; r < 4; ++r)
                    psum[mi][r] += fmaxf(acc[mi][ni][r] + bv, 0.f) * wv;
        }
#pragma unroll
        for (int mi = 0; mi < 4; ++mi)
#pragma unroll
            for (int r = 0; r < 4; ++r) {
                float v = psum[mi][r];
                v += __shfl_xor(v, 1, 64);
                v += __shfl_xor(v, 2, 64);
                v += __shfl_xor(v, 4, 64);
                v += __shfl_xor(v, 8, 64);
                if (c == 0) {
                    int row = mb + mi * 16 + q * 4 + r;
                    atomicAdd(out + row * BB + b, v);
                }
            }
    }
}

extern "C" void kernel_launch(void* const* d_in, const int* in_sizes, int n_in,
                              void* d_out, int out_size, void* d_ws, size_t ws_size,
                              hipStream_t stream) {
    const float* x  = (const float*)d_in[0];
    const float* w1 = (const float*)d_in[1];
    const float* b1 = (const float*)d_in[2];
    const float* w2 = (const float*)d_in[3];
    const float* b2 = (const float*)d_in[4];
    const float* w3 = (const float*)d_in[5];
    const float* b3 = (const float*)d_in[6];
    float* out = (float*)d_out;

    unsigned short* ws  = (unsigned short*)d_ws;
    unsigned short* xb  = ws;                               // 8*8192*128 bf16
    unsigned short* w1b = xb + (size_t)BB * T_TEST * KP;    // 8*512*128
    unsigned short* w2b = w1b + (size_t)BB * HH * KP;       // 8*512*512
    unsigned short* h1  = w2b + (size_t)BB * HH * HH;       // 8*8192*512

    prep_x<<<(BB * T_TEST * KP) / 256, 256, 0, stream>>>(x, xb);
    prep_w1<<<(BB * HH * KP) / 256, 256, 0, stream>>>(w1, w1b);
    prep_w2<<<(BB * HH * HH) / 256, 256, 0, stream>>>(w2, w2b);
    init_out<<<(T_TEST * BB) / 256, 256, 0, stream>>>(b3, out);

    gemm_kernel<1, KP / 32, KP><<<dim3(64, 4, 8), 256, 0, stream>>>(
        xb, w1b, b1, nullptr, h1, nullptr);
    gemm_kernel<2, HH / 32, HH><<<dim3(64, 4, 8), 256, 0, stream>>>(
        h1, w2b, b2, w3, nullptr, out);
}